// Round 22
// baseline (218.690 us; speedup 1.0000x reference)
//
#include <hip/hip_runtime.h>
#include <hip/hip_bf16.h>

#define NBAND 7
#define BBATCH 16
#define TSEQ 512
#define DMODEL 128
#define MBAND (BBATCH * TSEQ)               // 8192 rows per band
#define BANDE ((size_t)MBAND * DMODEL)      // 1,048,576 elements per band

typedef __attribute__((ext_vector_type(8))) short short8;
typedef __attribute__((ext_vector_type(4))) float f32x4;
typedef unsigned int u32;
typedef unsigned short u16;

__device__ __forceinline__ u16 f2bf(float x) {
  unsigned u = __float_as_uint(x);
  unsigned r = u + 0x7FFF + ((u >> 16) & 1);   // RNE
  return (u16)(r >> 16);
}
__device__ __forceinline__ u32 pack2(float a, float b) {
  return (u32)f2bf(a) | ((u32)f2bf(b) << 16);
}
__device__ __forceinline__ float b2f(u16 h) {
  return __uint_as_float((u32)h << 16);
}

// ===========================================================================
// Weight transpose+convert: src fp32 [K][N] -> dst bf16 [N][K]. Runs once.
// ===========================================================================
struct TSlice { const float* src; u16* dst; int K, N; };
struct TArgs { TSlice s[62]; };

__global__ __launch_bounds__(256) void wtrans_kernel(TArgs a) {
  TSlice sl = a.s[blockIdx.z];
  const int tk = (blockIdx.x & 7) * 64, tn = (blockIdx.x >> 3) * 64;
  if (tk >= sl.K || tn >= sl.N) return;
  __shared__ __align__(16) u16 T[64][72];
  const int tid = threadIdx.x;
  #pragma unroll
  for (int it = 0; it < 4; ++it) {
    int idx = tid + it * 256;                 // 1024 float4 units
    int k = idx >> 4, nq = (idx & 15) << 2;
    float4 v = *(const float4*)&sl.src[(size_t)(tk + k) * sl.N + tn + nq];
    T[nq + 0][k] = f2bf(v.x); T[nq + 1][k] = f2bf(v.y);
    T[nq + 2][k] = f2bf(v.z); T[nq + 3][k] = f2bf(v.w);
  }
  __syncthreads();
  #pragma unroll
  for (int it = 0; it < 2; ++it) {
    int idx = tid + it * 256;                 // 512 short8 units
    int n = idx >> 3, kq = (idx & 7) << 3;
    *(short8*)&sl.dst[(size_t)(tn + n) * sl.K + tk + kq] = *(const short8*)&T[n][kq];
  }
}

// ---------------------------------------------------------------------------
// MFMA part with register prefetch, bf16 A: acc[2][2] +=
// A(64xK bf16 [M][K]) @ WT(bf16 [N][K]), 64x64 tile at (m0, n0). K-step 32.
// ---------------------------------------------------------------------------
__device__ __forceinline__ void mfma_part_h(const u16* __restrict__ A,
                                            const u16* __restrict__ WT,
                                            int K, int m0, int n0, int tid,
                                            u16 (*As)[40], u16 (*Bs)[40],
                                            f32x4 acc[2][2]) {
  const int lane = tid & 63;
  const int wv = tid >> 6;
  const int wr = wv >> 1, wc = wv & 1;
  const int lr = lane & 15, k8 = lane >> 4;
  const int row = tid >> 2, kq = (tid & 3) << 3;

  const u16* Ar = &A[(size_t)(m0 + row) * K + kq];
  const u16* Br = &WT[(size_t)(n0 + row) * K + kq];
  short8 apre = *(const short8*)Ar;
  short8 bpre = *(const short8*)Br;

  for (int k0 = 0; k0 < K; k0 += 32) {
    __syncthreads();
    *(short8*)&As[row][kq] = apre;
    *(short8*)&Bs[row][kq] = bpre;
    if (k0 + 32 < K) {
      apre = *(const short8*)(Ar + k0 + 32);
      bpre = *(const short8*)(Br + k0 + 32);
    }
    __syncthreads();
    short8 a0 = *(const short8*)&As[wr * 32 + lr][k8 * 8];
    short8 a1 = *(const short8*)&As[wr * 32 + 16 + lr][k8 * 8];
    short8 b0 = *(const short8*)&Bs[wc * 32 + lr][k8 * 8];
    short8 b1 = *(const short8*)&Bs[wc * 32 + 16 + lr][k8 * 8];
    acc[0][0] = __builtin_amdgcn_mfma_f32_16x16x32_bf16(a0, b0, acc[0][0], 0, 0, 0);
    acc[0][1] = __builtin_amdgcn_mfma_f32_16x16x32_bf16(a0, b1, acc[0][1], 0, 0, 0);
    acc[1][0] = __builtin_amdgcn_mfma_f32_16x16x32_bf16(a1, b0, acc[1][0], 0, 0, 0);
    acc[1][1] = __builtin_amdgcn_mfma_f32_16x16x32_bf16(a1, b1, acc[1][1], 0, 0, 0);
  }
}

// Same but A is fp32 (converted to bf16 RNE at staging; prefetched).
__device__ __forceinline__ void mfma_part_f(const float* __restrict__ A,
                                            const u16* __restrict__ WT,
                                            int K, int m0, int n0, int tid,
                                            u16 (*As)[40], u16 (*Bs)[40],
                                            f32x4 acc[2][2]) {
  const int lane = tid & 63;
  const int wv = tid >> 6;
  const int wr = wv >> 1, wc = wv & 1;
  const int lr = lane & 15, k8 = lane >> 4;
  const int row = tid >> 2, kq = (tid & 3) << 3;

  const float* Ar = &A[(size_t)(m0 + row) * K + kq];
  const u16* Br = &WT[(size_t)(n0 + row) * K + kq];
  float4 ap0 = *(const float4*)Ar;
  float4 ap1 = *(const float4*)(Ar + 4);
  short8 bpre = *(const short8*)Br;

  for (int k0 = 0; k0 < K; k0 += 32) {
    __syncthreads();
    *(u32*)&As[row][kq]     = pack2(ap0.x, ap0.y);
    *(u32*)&As[row][kq + 2] = pack2(ap0.z, ap0.w);
    *(u32*)&As[row][kq + 4] = pack2(ap1.x, ap1.y);
    *(u32*)&As[row][kq + 6] = pack2(ap1.z, ap1.w);
    *(short8*)&Bs[row][kq] = bpre;
    if (k0 + 32 < K) {
      ap0 = *(const float4*)(Ar + k0 + 32);
      ap1 = *(const float4*)(Ar + k0 + 36);
      bpre = *(const short8*)(Br + k0 + 32);
    }
    __syncthreads();
    short8 a0 = *(const short8*)&As[wr * 32 + lr][k8 * 8];
    short8 a1 = *(const short8*)&As[wr * 32 + 16 + lr][k8 * 8];
    short8 b0 = *(const short8*)&Bs[wc * 32 + lr][k8 * 8];
    short8 b1 = *(const short8*)&Bs[wc * 32 + 16 + lr][k8 * 8];
    acc[0][0] = __builtin_amdgcn_mfma_f32_16x16x32_bf16(a0, b0, acc[0][0], 0, 0, 0);
    acc[0][1] = __builtin_amdgcn_mfma_f32_16x16x32_bf16(a0, b1, acc[0][1], 0, 0, 0);
    acc[1][0] = __builtin_amdgcn_mfma_f32_16x16x32_bf16(a1, b0, acc[1][0], 0, 0, 0);
    acc[1][1] = __builtin_amdgcn_mfma_f32_16x16x32_bf16(a1, b1, acc[1][1], 0, 0, 0);
  }
}

// ---------------------------------------------------------------------------
// Generalized batched GEMM: per-z descriptor (pointers pre-offset).
// grid (M/64, ymax, Z); blocks with n0 >= N[z] exit early.
// op 6: store bf16 transposed (packed uint2 along m): OH[n*MBAND + m].
// op 7: 6-part bridge.
// ---------------------------------------------------------------------------
struct ZD {
  const u16 *A, *A2, *WT, *WT2;
  const float* AF;              // fp32 A (used instead of A when non-null)
  const float* bias;
  const float* residF;
  const u16 *residH, *extraH;
  float* OF;
  u16* OH;
  int K, N, op;   // 0 store 1 gelu 2 sigmoid 3 residF+ 4 residH+sig*extraH->f32 5 residH+extraH*v 6 storeT 7 bridge
  int pad;
};
struct PArgs { ZD z[21]; };

__global__ __launch_bounds__(256) void gemm_b(PArgs p) {
  const ZD d = p.z[blockIdx.z];
  const int n0 = blockIdx.y * 64;
  if (n0 >= d.N) return;
  __shared__ __align__(16) u16 As[64][40];
  __shared__ __align__(16) u16 Bs[64][40];
  const int m0 = blockIdx.x * 64;
  const int tid = threadIdx.x;
  f32x4 acc[2][2] = {};

  if (d.op == 7) {
    const int bl[6] = {0, 1, 2, 4, 5, 6};
    #pragma unroll 1
    for (int s = 0; s < 6; ++s)
      mfma_part_h(d.A + (size_t)bl[s] * BANDE, d.WT + (size_t)s * 16384,
                  128, m0, n0, tid, As, Bs, acc);
  } else {
    if (d.AF) mfma_part_f(d.AF, d.WT, d.K, m0, n0, tid, As, Bs, acc);
    else      mfma_part_h(d.A,  d.WT, d.K, m0, n0, tid, As, Bs, acc);
    if (d.A2)
      mfma_part_h(d.A2, d.WT2, d.K, m0, n0, tid, As, Bs, acc);
  }

  const int lane = tid & 63;
  const int wv = tid >> 6;
  const int wr = wv >> 1, wc = wv & 1;
  const int lr = lane & 15, lg = lane >> 4;

  if (d.op == 6) {
    #pragma unroll
    for (int i = 0; i < 2; ++i) {
      #pragma unroll
      for (int j = 0; j < 2; ++j) {
        int mb = m0 + wr * 32 + i * 16 + lg * 4;
        int n = n0 + wc * 32 + j * 16 + lr;
        float bia = d.bias[n];
        uint2 st;
        st.x = pack2(acc[i][j][0] + bia, acc[i][j][1] + bia);
        st.y = pack2(acc[i][j][2] + bia, acc[i][j][3] + bia);
        *(uint2*)&d.OH[(size_t)n * MBAND + mb] = st;
      }
    }
    return;
  }

  #pragma unroll
  for (int i = 0; i < 2; ++i) {
    #pragma unroll
    for (int j = 0; j < 2; ++j) {
      #pragma unroll
      for (int r = 0; r < 4; ++r) {
        int m = m0 + wr * 32 + i * 16 + lg * 4 + r;
        int n = n0 + wc * 32 + j * 16 + lr;
        float v = acc[i][j][r];
        if (d.bias && d.op != 7) v += d.bias[n];
        size_t idx = (size_t)m * d.N + n;
        switch (d.op) {
          case 0: d.OH[idx] = f2bf(v); break;
          case 1: d.OH[idx] =
                    f2bf(0.5f * v * (1.f + erff(v * 0.70710678118654752f))); break;
          case 2: d.OH[idx] = f2bf(1.f / (1.f + __expf(-v))); break;
          case 3: d.OH[idx] = f2bf(d.residF[idx] + v); break;
          case 4: {
            float gate = 1.f / (1.f + __expf(-v));
            d.OF[idx] = b2f(d.residH[idx]) + gate * b2f(d.extraH[idx]);
          } break;
          case 5: {
            float gm = d.extraH ? b2f(d.extraH[idx]) : 1.f;
            d.OH[idx] = f2bf(b2f(d.residH[idx]) + gm * v);
          } break;
          case 7: {
            float bb = 0.f;
            #pragma unroll
            for (int s = 0; s < 6; ++s) bb += d.bias[s * 128 + n];
            d.OH[idx] = f2bf(v * (1.f / 6.f) + bb * (1.f / 6.f));
          } break;
        }
      }
    }
  }
}

// ---------------------------------------------------------------------------
// MFMA flash attention, ADJACENT q-tile pairing: 512 threads = 8 waves;
// pair pp covers q-tiles (7-2pp, 6-2pp): waves 0-3 own qtA = 7-2pp,
// waves 4-7 own qtA-1. K/V staged once per pair; light waves idle exactly
// one round. Rounds per pair-set: 8+6+4+2 = 20 (vs 26 for opposite pairing).
// Q in regs, pre-transposed V, K/V register prefetch; heavy pairs first.
// ---------------------------------------------------------------------------
__global__ __launch_bounds__(512) void attn_kernel(const u16* __restrict__ q,
                                                   const u16* __restrict__ k,
                                                   const u16* __restrict__ vT,
                                                   u16* __restrict__ o) {
  const int bx   = blockIdx.x;
  const int pp   = bx & 3;
  const int h    = (bx >> 2) & 1;
  const int b    = (bx >> 3) & 15;
  const int band = bx >> 7;
  const size_t rowbase = ((size_t)band * BBATCH + b) * TSEQ;
  const u16* vb = vT + (size_t)band * BANDE + (size_t)h * 64 * MBAND + (size_t)b * TSEQ;

  const int tid  = threadIdx.x;
  const int w    = tid >> 6;
  const int lane = tid & 63;
  const int lr   = lane & 15;
  const int lg   = lane >> 4;

  const int qtA = 7 - 2 * pp;                  // pairs (7,6),(5,4),(3,2),(1,0)
  const int qt_w = (w < 4) ? qtA : qtA - 1;
  const int wr4 = w & 3;

  __shared__ __align__(16) u16 Ks[64][72];
  __shared__ __align__(16) u16 Vs[64][72];
  __shared__ __align__(16) u16 Ps[8][16][72];

  short8 aq[2];
  {
    const u16* qp = &q[(rowbase + qt_w * 64 + wr4 * 16 + lr) * DMODEL + h * 64 + lg * 8];
    aq[0] = *(const short8*)qp;
    aq[1] = *(const short8*)(qp + 32);
  }

  const int sr = tid >> 3, sc8 = (tid & 7) << 3;
  short8 kpre = *(const short8*)&k[(rowbase + sr) * DMODEL + h * 64 + sc8];
  short8 vpre = *(const short8*)&vb[(size_t)sr * MBAND + sc8];

  f32x4 oacc[4] = {};
  float m[4], l[4];
  #pragma unroll
  for (int r = 0; r < 4; ++r) { m[r] = -1e30f; l[r] = 0.f; }

  for (int kt = 0; kt <= qtA; ++kt) {
    __syncthreads();
    *(short8*)&Ks[sr][sc8] = kpre;
    *(short8*)&Vs[sr][sc8] = vpre;
    if (kt < qtA) {
      int nt = kt + 1;
      kpre = *(const short8*)&k[(rowbase + nt * 64 + sr) * DMODEL + h * 64 + sc8];
      vpre = *(const short8*)&vb[(size_t)sr * MBAND + nt * 64 + sc8];
    }
    __syncthreads();

    if (kt <= qt_w) {
      f32x4 s[4] = {};
      #pragma unroll
      for (int c = 0; c < 2; ++c) {
        short8 a = aq[c];
        #pragma unroll
        for (int j = 0; j < 4; ++j) {
          short8 bb = *(const short8*)&Ks[j * 16 + lr][c * 32 + lg * 8];
          s[j] = __builtin_amdgcn_mfma_f32_16x16x32_bf16(a, bb, s[j], 0, 0, 0);
        }
      }
      #pragma unroll
      for (int j = 0; j < 4; ++j)
        #pragma unroll
        for (int r = 0; r < 4; ++r)
          s[j][r] *= 0.125f;

      if (kt == qt_w) {
        #pragma unroll
        for (int j = 0; j < 4; ++j)
          #pragma unroll
          for (int r = 0; r < 4; ++r) {
            int row = wr4 * 16 + lg * 4 + r;
            int col = j * 16 + lr;
            if (col > row) s[j][r] = -1e30f;
          }
      }

      float mx[4], al[4];
      #pragma unroll
      for (int r = 0; r < 4; ++r)
        mx[r] = fmaxf(fmaxf(s[0][r], s[1][r]), fmaxf(s[2][r], s[3][r]));
      #pragma unroll
      for (int off = 1; off <= 8; off <<= 1)
        #pragma unroll
        for (int r = 0; r < 4; ++r)
          mx[r] = fmaxf(mx[r], __shfl_xor(mx[r], off));
      #pragma unroll
      for (int r = 0; r < 4; ++r) {
        float mn = fmaxf(m[r], mx[r]);
        al[r] = __expf(m[r] - mn);
        m[r] = mn;
      }
      float rs[4] = {0.f, 0.f, 0.f, 0.f};
      #pragma unroll
      for (int j = 0; j < 4; ++j)
        #pragma unroll
        for (int r = 0; r < 4; ++r) {
          float pe = __expf(s[j][r] - m[r]);
          s[j][r] = pe;
          rs[r] += pe;
        }
      #pragma unroll
      for (int off = 1; off <= 8; off <<= 1)
        #pragma unroll
        for (int r = 0; r < 4; ++r)
          rs[r] += __shfl_xor(rs[r], off);
      #pragma unroll
      for (int r = 0; r < 4; ++r) l[r] = l[r] * al[r] + rs[r];

      #pragma unroll
      for (int j = 0; j < 4; ++j)
        #pragma unroll
        for (int r = 0; r < 4; ++r)
          oacc[j][r] *= al[r];

      #pragma unroll
      for (int j = 0; j < 4; ++j)
        #pragma unroll
        for (int r = 0; r < 4; ++r)
          Ps[w][lg * 4 + r][j * 16 + lr] = f2bf(s[j][r]);

      #pragma unroll
      for (int c = 0; c < 2; ++c) {
        short8 a = *(const short8*)&Ps[w][lr][c * 32 + lg * 8];
        #pragma unroll
        for (int j = 0; j < 4; ++j) {
          short8 bb = *(const short8*)&Vs[j * 16 + lr][c * 32 + lg * 8];
          oacc[j] = __builtin_amdgcn_mfma_f32_16x16x32_bf16(a, bb, oacc[j], 0, 0, 0);
        }
      }
    }
  }

  float inv[4];
  #pragma unroll
  for (int r = 0; r < 4; ++r) inv[r] = 1.f / l[r];
  #pragma unroll
  for (int j = 0; j < 4; ++j)
    #pragma unroll
    for (int r = 0; r < 4; ++r) {
      size_t row = rowbase + qt_w * 64 + wr4 * 16 + lg * 4 + r;
      o[row * DMODEL + h * 64 + j * 16 + lr] = f2bf(oacc[j][r] * inv[r]);
    }
}

// ---------------------------------------------------------------------------
struct LNA {
  const u16* x;
  u16* xn;
  const float* ls[7];
  const float* lb[7];
};

__global__ __launch_bounds__(256) void ln_kernel(LNA p) {
  const int tid = threadIdx.x;
  const int rr = tid >> 6, lane = tid & 63;
  const size_t row = (size_t)blockIdx.x * 4 + rr;
  u32 wv = *(const u32*)&p.x[row * DMODEL + 2 * lane];
  float a = b2f((u16)wv), b = b2f((u16)(wv >> 16));
  float s = a + b;
  #pragma unroll
  for (int off = 32; off; off >>= 1) s += __shfl_xor(s, off);
  float mean = s * (1.f / 128.f);
  float da = a - mean, db = b - mean;
  float vs = da * da + db * db;
  #pragma unroll
  for (int off = 32; off; off >>= 1) vs += __shfl_xor(vs, off);
  float rstd = rsqrtf(vs * (1.f / 128.f) + 1e-5f);
  int band = (int)(row >> 13);
  const float* ls = p.ls[band];
  const float* lb = p.lb[band];
  *(u32*)&p.xn[row * DMODEL + 2 * lane] =
      pack2(da * rstd * ls[2 * lane] + lb[2 * lane],
            db * rstd * ls[2 * lane + 1] + lb[2 * lane + 1]);
}

// ---------------------------------------------------------------------------
extern "C" void kernel_launch(void* const* d_in, const int* in_sizes, int n_in,
                              void* d_out, int out_size, void* d_ws, size_t ws_size,
                              hipStream_t stream) {
  bool dict = (in_sizes[2] != 896);
  const float* bands = (const float*)d_in[0];
  const float* Wq = (const float*)d_in[1];
  const float *Wk, *Wv, *Wo, *bq, *bk, *bv, *bo;
  if (dict) {
    Wk = (const float*)d_in[2]; Wv = (const float*)d_in[3]; Wo = (const float*)d_in[4];
    bq = (const float*)d_in[5]; bk = (const float*)d_in[6];
    bv = (const float*)d_in[7]; bo = (const float*)d_in[8];
  } else {
    bq = (const float*)d_in[2]; Wk = (const float*)d_in[3]; bk = (const float*)d_in[4];
    Wv = (const float*)d_in[5]; bv = (const float*)d_in[6];
    Wo = (const float*)d_in[7]; bo = (const float*)d_in[8];
  }
  const float* g_ls = (const float*)d_in[9];
  const float* g_lb = (const float*)d_in[10];
  const float* g_w1 = (const float*)d_in[11];
  const float* g_b1 = (const float*)d_in[12];
  const float* g_w2 = (const float*)d_in[13];
  const float* g_b2 = (const float*)d_in[14];
  const float* g_wg = (const float*)d_in[15];
  const float* g_bg = (const float*)d_in[16];
  const float* h_ls = (const float*)d_in[17];
  const float* h_lb = (const float*)d_in[18];
  const float* h_w1 = (const float*)d_in[19];
  const float* h_b1 = (const float*)d_in[20];
  const float* h_w2 = (const float*)d_in[21];
  const float* h_b2 = (const float*)d_in[22];
  const float* r_ls = (const float*)d_in[23];
  const float* r_lb = (const float*)d_in[24];
  const float* r_w1 = (const float*)d_in[25];
  const float* r_b1 = (const float*)d_in[26];
  const float* r_w2 = (const float*)d_in[27];
  const float* r_b2 = (const float*)d_in[28];
  const float* wp_w = (const float*)d_in[29];
  const float* wp_b = (const float*)d_in[30];
  const float* wg_w = (const float*)d_in[31];
  const float* wg_b = (const float*)d_in[32];
  const float* br_w = (const float*)d_in[33];
  const float* br_b = (const float*)d_in[34];
  const float* bg_w = (const float*)d_in[35];
  const float* bg_b = (const float*)d_in[36];
  float* out = (float*)d_out;

  const float* lsP[7] = {g_ls, g_ls + 128, g_ls + 256, h_ls, h_ls + 128, r_ls, r_ls + 128};
  const float* lbP[7] = {g_lb, g_lb + 128, g_lb + 256, h_lb, h_lb + 128, r_lb, r_lb + 128};
  const float* b1p[7] = {g_b1, g_b1 + 256, g_b1 + 512,
                         h_b1, h_b1 + 384, r_b1, r_b1 + 512};
  const float* b2p[7] = {g_b2, g_b2 + 128, g_b2 + 256,
                         h_b2, h_b2 + 128, r_b2, r_b2 + 128};
  const int hN[7] = {256, 256, 256, 384, 384, 512, 512};

  // ---- workspace: bf16 activations (hidden arena holds ALL bands) ----
  const size_t HIDSZ = (size_t)MBAND * 2560;   // 3*256 + 2*384 + 2*512
  u16* H = (u16*)d_ws;
  u16* hidh = H;                         // HIDSZ (later overlays info/bridge)
  u16* qh = H + HIDSZ;
  u16* kh = qh + 7 * BANDE;
  u16* vh = kh + 7 * BANDE;              // holds vT[band][h][dim][m]
  u16* oh = vh + 7 * BANDE;
  u16* wt = oh + 7 * BANDE;              // transposed weights (bf16 [N][K])
  u16* wtQ   = wt;
  u16* wtK   = wtQ + 7 * 16384;
  u16* wtV   = wtK + 7 * 16384;
  u16* wtO   = wtV + 7 * 16384;
  u16* wtGwg = wtO + 7 * 16384;
  u16* wtWp  = wtGwg + 3 * 16384;
  u16* wtBr  = wtWp + 3 * 16384;
  u16* wtWg  = wtBr + 6 * 16384;         // 3 i x 2 K-parts
  u16* wtBg  = wtWg + 6 * 16384;         // 2 K-parts
  u16* wtG1  = wtBg + 2 * 16384;
  u16* wtH1  = wtG1 + 3 * 32768;
  u16* wtR1  = wtH1 + 2 * 49152;
  u16* wtG2  = wtR1 + 2 * 65536;
  u16* wtH2  = wtG2 + 3 * 32768;
  u16* wtR2  = wtH2 + 2 * 49152;
  u16* xh = qh;
  u16* xnh = kh;
  u16* gateh = vh;
  u16* yh = oh;
  u16* infoh = hidh;
  u16* bridgeh = hidh + 6 * BANDE;

  size_t hOff[7];
  {
    size_t acc = 0;
    for (int n = 0; n < 7; ++n) { hOff[n] = acc; acc += (size_t)MBAND * hN[n]; }
  }
  u16* wtW1s[7] = {wtG1, wtG1 + 32768, wtG1 + 65536,
                   wtH1, wtH1 + 49152, wtR1, wtR1 + 65536};
  u16* wtW2s[7] = {wtG2, wtG2 + 32768, wtG2 + 65536,
                   wtH2, wtH2 + 49152, wtR2, wtR2 + 65536};

  auto LP = [&](PArgs& p, int Z, int ymax) {
    dim3 grid(MBAND / 64, ymax, Z);
    gemm_b<<<grid, dim3(256), 0, stream>>>(p);
  };

  // 0. transpose all weights once
  {
    TArgs ta{};
    int ns = 0;
    auto add = [&](const float* s, u16* d, int K, int N) {
      ta.s[ns].src = s; ta.s[ns].dst = d; ta.s[ns].K = K; ta.s[ns].N = N; ++ns;
    };
    for (int z = 0; z < 7; ++z) add(Wq + z * 16384, wtQ + z * 16384, 128, 128);
    for (int z = 0; z < 7; ++z) add(Wk + z * 16384, wtK + z * 16384, 128, 128);
    for (int z = 0; z < 7; ++z) add(Wv + z * 16384, wtV + z * 16384, 128, 128);
    for (int z = 0; z < 7; ++z) add(Wo + z * 16384, wtO + z * 16384, 128, 128);
    for (int i = 0; i < 3; ++i) add(g_wg + i * 16384, wtGwg + i * 16384, 128, 128);
    for (int i = 0; i < 3; ++i) add(wp_w + i * 16384, wtWp + i * 16384, 128, 128);
    for (int j = 0; j < 6; ++j) add(br_w + j * 16384, wtBr + j * 16384, 128, 128);
    for (int i = 0; i < 3; ++i) {
      add(wg_w + i * 32768,         wtWg + (size_t)(2 * i) * 16384,     128, 128);
      add(wg_w + i * 32768 + 16384, wtWg + (size_t)(2 * i + 1) * 16384, 128, 128);
    }
    add(bg_w,         wtBg,         128, 128);
    add(bg_w + 16384, wtBg + 16384, 128, 128);
    for (int i = 0; i < 3; ++i) add(g_w1 + i * 32768, wtG1 + i * 32768, 128, 256);
    for (int i = 0; i < 2; ++i) add(h_w1 + i * 49152, wtH1 + i * 49152, 128, 384);
    for (int i = 0; i < 2; ++i) add(r_w1 + i * 65536, wtR1 + i * 65536, 128, 512);
    for (int i = 0; i < 3; ++i) add(g_w2 + i * 32768, wtG2 + i * 32768, 256, 128);
    for (int i = 0; i < 2; ++i) add(h_w2 + i * 49152, wtH2 + i * 49152, 384, 128);
    for (int i = 0; i < 2; ++i) add(r_w2 + i * 65536, wtR2 + i * 65536, 512, 128);
    wtrans_kernel<<<dim3(64, 1, 62), dim3(256), 0, stream>>>(ta);
  }

  // 1. QKV merged: one dispatch, Z=21. A = fp32 bands (convert at staging).
  //    V entries store transposed (op 6, packed uint2).
  {
    PArgs p{};
    const u16* wtQKV[3] = {wtQ, wtK, wtV};
    const float* bqkv[3] = {bq, bk, bv};
    u16* oqkv[3] = {qh, kh, vh};
    for (int w = 0; w < 3; ++w)
      for (int band = 0; band < 7; ++band) {
        ZD& d = p.z[w * 7 + band];
        d.AF = bands + (size_t)band * BANDE;
        d.WT = wtQKV[w] + (size_t)band * 16384;
        d.bias = bqkv[w] + band * 128;
        d.OH = oqkv[w] + (size_t)band * BANDE;
        d.K = 128; d.N = 128; d.op = (w == 2) ? 6 : 0;
      }
    LP(p, 21, 2);
  }

  // 2. attention (adjacent-paired q-tiles, 512 threads)
  attn_kernel<<<dim3(NBAND * BBATCH * 2 * 4), dim3(512), 0, stream>>>(qh, kh, vh, oh);

  // 3. x = bands + o @ Wo + bo
  {
    PArgs p{};
    for (int band = 0; band < 7; ++band) {
      ZD& d = p.z[band];
      d.A = oh + (size_t)band * BANDE;
      d.WT = wtO + (size_t)band * 16384;
      d.bias = bo + band * 128;
      d.residF = bands + (size_t)band * BANDE;
      d.OH = xh + (size_t)band * BANDE;
      d.K = 128; d.N = 128; d.op = 3;
    }
    LP(p, 7, 2);
  }

  // 4. LN
  {
    LNA p{};
    p.x = xh; p.xn = xnh;
    for (int n = 0; n < 7; ++n) { p.ls[n] = lsP[n]; p.lb[n] = lbP[n]; }
    ln_kernel<<<dim3(NBAND * MBAND / 4), dim3(256), 0, stream>>>(p);
  }

  // 5. geo gates + all MLP1 merged: Z=10, y=8 (early exit past N)
  {
    PArgs p{};
    for (int z = 0; z < 3; ++z) {
      ZD& d = p.z[z];
      d.A = xh + (size_t)z * BANDE;
      d.WT = wtGwg + (size_t)z * 16384;
      d.bias = g_bg + z * 128;
      d.OH = gateh + (size_t)z * BANDE;
      d.K = 128; d.N = 128; d.op = 2;
    }
    for (int band = 0; band < 7; ++band) {
      ZD& d = p.z[3 + band];
      d.A = xnh + (size_t)band * BANDE;
      d.WT = wtW1s[band];
      d.bias = b1p[band];
      d.OH = hidh + hOff[band];
      d.K = 128; d.N = hN[band]; d.op = 1;
    }
    LP(p, 10, 8);
  }

  // 6. MLP2 merged: Z=7 (per-z K)
  {
    PArgs p{};
    for (int band = 0; band < 7; ++band) {
      ZD& d = p.z[band];
      d.A = hidh + hOff[band];
      d.WT = wtW2s[band];
      d.bias = b2p[band];
      d.residH = xh + (size_t)band * BANDE;
      d.extraH = (band < 3) ? gateh + (size_t)band * BANDE : nullptr;
      d.OH = yh + (size_t)band * BANDE;
      d.K = hN[band]; d.N = 128; d.op = 5;
    }
    LP(p, 7, 2);
  }

  // 7. info (z=0..5) + bridge (z=6, op 7): one dispatch
  {
    PArgs p{};
    for (int z = 0; z < 6; ++z) {
      int t = (z < 3) ? z : z + 1;
      int src = 6 - t;
      int i = (t < 3) ? t : 6 - t;
      ZD& d = p.z[z];
      d.A = yh + (size_t)src * BANDE;
      d.WT = wtWp + (size_t)i * 16384;
      d.bias = wp_b + i * 128;
      d.OH = infoh + (size_t)z * BANDE;
      d.K = 128; d.N = 128; d.op = 0;
    }
    {
      ZD& d = p.z[6];
      d.A = yh;
      d.WT = wtBr;
      d.bias = br_b;
      d.OH = bridgeh;
      d.K = 128; d.N = 128; d.op = 7;
    }
    LP(p, 7, 2);
  }

  // 8. final gates + band-3 merged: Z=7, fp32 out
  {
    PArgs p{};
    for (int z = 0; z < 6; ++z) {
      int t = (z < 3) ? z : z + 1;
      int i = (t < 3) ? t : 6 - t;
      ZD& d = p.z[z];
      d.A = yh + (size_t)t * BANDE;
      d.WT = wtWg + (size_t)(2 * i) * 16384;
      d.A2 = infoh + (size_t)z * BANDE;
      d.WT2 = wtWg + (size_t)(2 * i + 1) * 16384;
      d.bias = wg_b + i * 128;
      d.residH = yh + (size_t)t * BANDE;
      d.extraH = infoh + (size_t)z * BANDE;
      d.OF = out + (size_t)t * BANDE;
      d.K = 128; d.N = 128; d.op = 4;
    }
    {
      ZD& d = p.z[6];
      d.A = yh + 3 * BANDE;
      d.WT = wtBg;
      d.A2 = bridgeh;
      d.WT2 = wtBg + 16384;
      d.bias = bg_b;
      d.residH = yh + 3 * BANDE;
      d.extraH = bridgeh;
      d.OF = out + 3 * BANDE;
      d.K = 128; d.N = 128; d.op = 4;
    }
    LP(p, 7, 2);
  }
}

// Round 23
// 207.034 us; speedup vs baseline: 1.0563x; 1.0563x over previous
//
#include <hip/hip_runtime.h>
#include <hip/hip_bf16.h>

#define NBAND 7
#define BBATCH 16
#define TSEQ 512
#define DMODEL 128
#define MBAND (BBATCH * TSEQ)               // 8192 rows per band
#define BANDE ((size_t)MBAND * DMODEL)      // 1,048,576 elements per band

typedef __attribute__((ext_vector_type(8))) short short8;
typedef __attribute__((ext_vector_type(4))) float f32x4;
typedef unsigned int u32;
typedef unsigned short u16;

__device__ __forceinline__ u16 f2bf(float x) {
  unsigned u = __float_as_uint(x);
  unsigned r = u + 0x7FFF + ((u >> 16) & 1);   // RNE
  return (u16)(r >> 16);
}
__device__ __forceinline__ u32 pack2(float a, float b) {
  return (u32)f2bf(a) | ((u32)f2bf(b) << 16);
}
__device__ __forceinline__ float b2f(u16 h) {
  return __uint_as_float((u32)h << 16);
}

// ===========================================================================
// Weight transpose+convert: src fp32 [K][N] -> dst bf16 [N][K]. Runs once.
// ===========================================================================
struct TSlice { const float* src; u16* dst; int K, N; };
struct TArgs { TSlice s[62]; };

__global__ __launch_bounds__(256) void wtrans_kernel(TArgs a) {
  TSlice sl = a.s[blockIdx.z];
  const int tk = (blockIdx.x & 7) * 64, tn = (blockIdx.x >> 3) * 64;
  if (tk >= sl.K || tn >= sl.N) return;
  __shared__ __align__(16) u16 T[64][72];
  const int tid = threadIdx.x;
  #pragma unroll
  for (int it = 0; it < 4; ++it) {
    int idx = tid + it * 256;                 // 1024 float4 units
    int k = idx >> 4, nq = (idx & 15) << 2;
    float4 v = *(const float4*)&sl.src[(size_t)(tk + k) * sl.N + tn + nq];
    T[nq + 0][k] = f2bf(v.x); T[nq + 1][k] = f2bf(v.y);
    T[nq + 2][k] = f2bf(v.z); T[nq + 3][k] = f2bf(v.w);
  }
  __syncthreads();
  #pragma unroll
  for (int it = 0; it < 2; ++it) {
    int idx = tid + it * 256;                 // 512 short8 units
    int n = idx >> 3, kq = (idx & 7) << 3;
    *(short8*)&sl.dst[(size_t)(tn + n) * sl.K + tk + kq] = *(const short8*)&T[n][kq];
  }
}

// ---------------------------------------------------------------------------
// MFMA part with register prefetch, bf16 A: acc[2][2] +=
// A(64xK bf16 [M][K]) @ WT(bf16 [N][K]), 64x64 tile at (m0, n0). K-step 32.
// ---------------------------------------------------------------------------
__device__ __forceinline__ void mfma_part_h(const u16* __restrict__ A,
                                            const u16* __restrict__ WT,
                                            int K, int m0, int n0, int tid,
                                            u16 (*As)[40], u16 (*Bs)[40],
                                            f32x4 acc[2][2]) {
  const int lane = tid & 63;
  const int wv = tid >> 6;
  const int wr = wv >> 1, wc = wv & 1;
  const int lr = lane & 15, k8 = lane >> 4;
  const int row = tid >> 2, kq = (tid & 3) << 3;

  const u16* Ar = &A[(size_t)(m0 + row) * K + kq];
  const u16* Br = &WT[(size_t)(n0 + row) * K + kq];
  short8 apre = *(const short8*)Ar;
  short8 bpre = *(const short8*)Br;

  for (int k0 = 0; k0 < K; k0 += 32) {
    __syncthreads();
    *(short8*)&As[row][kq] = apre;
    *(short8*)&Bs[row][kq] = bpre;
    if (k0 + 32 < K) {
      apre = *(const short8*)(Ar + k0 + 32);
      bpre = *(const short8*)(Br + k0 + 32);
    }
    __syncthreads();
    short8 a0 = *(const short8*)&As[wr * 32 + lr][k8 * 8];
    short8 a1 = *(const short8*)&As[wr * 32 + 16 + lr][k8 * 8];
    short8 b0 = *(const short8*)&Bs[wc * 32 + lr][k8 * 8];
    short8 b1 = *(const short8*)&Bs[wc * 32 + 16 + lr][k8 * 8];
    acc[0][0] = __builtin_amdgcn_mfma_f32_16x16x32_bf16(a0, b0, acc[0][0], 0, 0, 0);
    acc[0][1] = __builtin_amdgcn_mfma_f32_16x16x32_bf16(a0, b1, acc[0][1], 0, 0, 0);
    acc[1][0] = __builtin_amdgcn_mfma_f32_16x16x32_bf16(a1, b0, acc[1][0], 0, 0, 0);
    acc[1][1] = __builtin_amdgcn_mfma_f32_16x16x32_bf16(a1, b1, acc[1][1], 0, 0, 0);
  }
}

// Same but A is fp32 (converted to bf16 RNE at staging; prefetched).
__device__ __forceinline__ void mfma_part_f(const float* __restrict__ A,
                                            const u16* __restrict__ WT,
                                            int K, int m0, int n0, int tid,
                                            u16 (*As)[40], u16 (*Bs)[40],
                                            f32x4 acc[2][2]) {
  const int lane = tid & 63;
  const int wv = tid >> 6;
  const int wr = wv >> 1, wc = wv & 1;
  const int lr = lane & 15, k8 = lane >> 4;
  const int row = tid >> 2, kq = (tid & 3) << 3;

  const float* Ar = &A[(size_t)(m0 + row) * K + kq];
  const u16* Br = &WT[(size_t)(n0 + row) * K + kq];
  float4 ap0 = *(const float4*)Ar;
  float4 ap1 = *(const float4*)(Ar + 4);
  short8 bpre = *(const short8*)Br;

  for (int k0 = 0; k0 < K; k0 += 32) {
    __syncthreads();
    *(u32*)&As[row][kq]     = pack2(ap0.x, ap0.y);
    *(u32*)&As[row][kq + 2] = pack2(ap0.z, ap0.w);
    *(u32*)&As[row][kq + 4] = pack2(ap1.x, ap1.y);
    *(u32*)&As[row][kq + 6] = pack2(ap1.z, ap1.w);
    *(short8*)&Bs[row][kq] = bpre;
    if (k0 + 32 < K) {
      ap0 = *(const float4*)(Ar + k0 + 32);
      ap1 = *(const float4*)(Ar + k0 + 36);
      bpre = *(const short8*)(Br + k0 + 32);
    }
    __syncthreads();
    short8 a0 = *(const short8*)&As[wr * 32 + lr][k8 * 8];
    short8 a1 = *(const short8*)&As[wr * 32 + 16 + lr][k8 * 8];
    short8 b0 = *(const short8*)&Bs[wc * 32 + lr][k8 * 8];
    short8 b1 = *(const short8*)&Bs[wc * 32 + 16 + lr][k8 * 8];
    acc[0][0] = __builtin_amdgcn_mfma_f32_16x16x32_bf16(a0, b0, acc[0][0], 0, 0, 0);
    acc[0][1] = __builtin_amdgcn_mfma_f32_16x16x32_bf16(a0, b1, acc[0][1], 0, 0, 0);
    acc[1][0] = __builtin_amdgcn_mfma_f32_16x16x32_bf16(a1, b0, acc[1][0], 0, 0, 0);
    acc[1][1] = __builtin_amdgcn_mfma_f32_16x16x32_bf16(a1, b1, acc[1][1], 0, 0, 0);
  }
}

// ---------------------------------------------------------------------------
// Generalized batched GEMM: per-z descriptor (pointers pre-offset).
// grid (M/64, ymax, Z); blocks with n0 >= N[z] exit early.
// op 6: store bf16 transposed (packed uint2 along m): OH[n*MBAND + m].
// op 7: 6-part bridge.
// ---------------------------------------------------------------------------
struct ZD {
  const u16 *A, *A2, *WT, *WT2;
  const float* AF;              // fp32 A (used instead of A when non-null)
  const float* bias;
  const float* residF;
  const u16 *residH, *extraH;
  float* OF;
  u16* OH;
  int K, N, op;   // 0 store 1 gelu 2 sigmoid 3 residF+ 4 residH+sig*extraH->f32 5 residH+extraH*v 6 storeT 7 bridge
  int pad;
};
struct PArgs { ZD z[21]; };

__global__ __launch_bounds__(256) void gemm_b(PArgs p) {
  const ZD d = p.z[blockIdx.z];
  const int n0 = blockIdx.y * 64;
  if (n0 >= d.N) return;
  __shared__ __align__(16) u16 As[64][40];
  __shared__ __align__(16) u16 Bs[64][40];
  const int m0 = blockIdx.x * 64;
  const int tid = threadIdx.x;
  f32x4 acc[2][2] = {};

  if (d.op == 7) {
    const int bl[6] = {0, 1, 2, 4, 5, 6};
    #pragma unroll 1
    for (int s = 0; s < 6; ++s)
      mfma_part_h(d.A + (size_t)bl[s] * BANDE, d.WT + (size_t)s * 16384,
                  128, m0, n0, tid, As, Bs, acc);
  } else {
    if (d.AF) mfma_part_f(d.AF, d.WT, d.K, m0, n0, tid, As, Bs, acc);
    else      mfma_part_h(d.A,  d.WT, d.K, m0, n0, tid, As, Bs, acc);
    if (d.A2)
      mfma_part_h(d.A2, d.WT2, d.K, m0, n0, tid, As, Bs, acc);
  }

  const int lane = tid & 63;
  const int wv = tid >> 6;
  const int wr = wv >> 1, wc = wv & 1;
  const int lr = lane & 15, lg = lane >> 4;

  if (d.op == 6) {
    #pragma unroll
    for (int i = 0; i < 2; ++i) {
      #pragma unroll
      for (int j = 0; j < 2; ++j) {
        int mb = m0 + wr * 32 + i * 16 + lg * 4;
        int n = n0 + wc * 32 + j * 16 + lr;
        float bia = d.bias[n];
        uint2 st;
        st.x = pack2(acc[i][j][0] + bia, acc[i][j][1] + bia);
        st.y = pack2(acc[i][j][2] + bia, acc[i][j][3] + bia);
        *(uint2*)&d.OH[(size_t)n * MBAND + mb] = st;
      }
    }
    return;
  }

  #pragma unroll
  for (int i = 0; i < 2; ++i) {
    #pragma unroll
    for (int j = 0; j < 2; ++j) {
      #pragma unroll
      for (int r = 0; r < 4; ++r) {
        int m = m0 + wr * 32 + i * 16 + lg * 4 + r;
        int n = n0 + wc * 32 + j * 16 + lr;
        float v = acc[i][j][r];
        if (d.bias && d.op != 7) v += d.bias[n];
        size_t idx = (size_t)m * d.N + n;
        switch (d.op) {
          case 0: d.OH[idx] = f2bf(v); break;
          case 1: d.OH[idx] =
                    f2bf(0.5f * v * (1.f + erff(v * 0.70710678118654752f))); break;
          case 2: d.OH[idx] = f2bf(1.f / (1.f + __expf(-v))); break;
          case 3: d.OH[idx] = f2bf(d.residF[idx] + v); break;
          case 4: {
            float gate = 1.f / (1.f + __expf(-v));
            d.OF[idx] = b2f(d.residH[idx]) + gate * b2f(d.extraH[idx]);
          } break;
          case 5: {
            float gm = d.extraH ? b2f(d.extraH[idx]) : 1.f;
            d.OH[idx] = f2bf(b2f(d.residH[idx]) + gm * v);
          } break;
          case 7: {
            float bb = 0.f;
            #pragma unroll
            for (int s = 0; s < 6; ++s) bb += d.bias[s * 128 + n];
            d.OH[idx] = f2bf(v * (1.f / 6.f) + bb * (1.f / 6.f));
          } break;
        }
      }
    }
  }
}

// ---------------------------------------------------------------------------
// MFMA flash attention, q-tile PAIRED: 512 threads = 8 waves; waves 0-3 own
// q-tile qtA = 7-pp (heavy), waves 4-7 own qtB = pp. K/V staged ONCE per
// pair; loop runs to qtA; light-tile waves skip compute past their bound.
// Q in regs, pre-transposed V, K/V register prefetch.
// ---------------------------------------------------------------------------
__global__ __launch_bounds__(512) void attn_kernel(const u16* __restrict__ q,
                                                   const u16* __restrict__ k,
                                                   const u16* __restrict__ vT,
                                                   u16* __restrict__ o) {
  const int bx   = blockIdx.x;
  const int pp   = bx & 3;
  const int h    = (bx >> 2) & 1;
  const int b    = (bx >> 3) & 15;
  const int band = bx >> 7;
  const size_t rowbase = ((size_t)band * BBATCH + b) * TSEQ;
  const u16* vb = vT + (size_t)band * BANDE + (size_t)h * 64 * MBAND + (size_t)b * TSEQ;

  const int tid  = threadIdx.x;
  const int w    = tid >> 6;
  const int lane = tid & 63;
  const int lr   = lane & 15;
  const int lg   = lane >> 4;

  const int qtA = 7 - pp;
  const int qt_w = (w < 4) ? qtA : pp;
  const int wr4 = w & 3;

  __shared__ __align__(16) u16 Ks[64][72];
  __shared__ __align__(16) u16 Vs[64][72];
  __shared__ __align__(16) u16 Ps[8][16][72];

  short8 aq[2];
  {
    const u16* qp = &q[(rowbase + qt_w * 64 + wr4 * 16 + lr) * DMODEL + h * 64 + lg * 8];
    aq[0] = *(const short8*)qp;
    aq[1] = *(const short8*)(qp + 32);
  }

  const int sr = tid >> 3, sc8 = (tid & 7) << 3;
  short8 kpre = *(const short8*)&k[(rowbase + sr) * DMODEL + h * 64 + sc8];
  short8 vpre = *(const short8*)&vb[(size_t)sr * MBAND + sc8];

  f32x4 oacc[4] = {};
  float m[4], l[4];
  #pragma unroll
  for (int r = 0; r < 4; ++r) { m[r] = -1e30f; l[r] = 0.f; }

  for (int kt = 0; kt <= qtA; ++kt) {
    __syncthreads();
    *(short8*)&Ks[sr][sc8] = kpre;
    *(short8*)&Vs[sr][sc8] = vpre;
    if (kt < qtA) {
      int nt = kt + 1;
      kpre = *(const short8*)&k[(rowbase + nt * 64 + sr) * DMODEL + h * 64 + sc8];
      vpre = *(const short8*)&vb[(size_t)sr * MBAND + nt * 64 + sc8];
    }
    __syncthreads();

    if (kt <= qt_w) {
      f32x4 s[4] = {};
      #pragma unroll
      for (int c = 0; c < 2; ++c) {
        short8 a = aq[c];
        #pragma unroll
        for (int j = 0; j < 4; ++j) {
          short8 bb = *(const short8*)&Ks[j * 16 + lr][c * 32 + lg * 8];
          s[j] = __builtin_amdgcn_mfma_f32_16x16x32_bf16(a, bb, s[j], 0, 0, 0);
        }
      }
      #pragma unroll
      for (int j = 0; j < 4; ++j)
        #pragma unroll
        for (int r = 0; r < 4; ++r)
          s[j][r] *= 0.125f;

      if (kt == qt_w) {
        #pragma unroll
        for (int j = 0; j < 4; ++j)
          #pragma unroll
          for (int r = 0; r < 4; ++r) {
            int row = wr4 * 16 + lg * 4 + r;
            int col = j * 16 + lr;
            if (col > row) s[j][r] = -1e30f;
          }
      }

      float mx[4], al[4];
      #pragma unroll
      for (int r = 0; r < 4; ++r)
        mx[r] = fmaxf(fmaxf(s[0][r], s[1][r]), fmaxf(s[2][r], s[3][r]));
      #pragma unroll
      for (int off = 1; off <= 8; off <<= 1)
        #pragma unroll
        for (int r = 0; r < 4; ++r)
          mx[r] = fmaxf(mx[r], __shfl_xor(mx[r], off));
      #pragma unroll
      for (int r = 0; r < 4; ++r) {
        float mn = fmaxf(m[r], mx[r]);
        al[r] = __expf(m[r] - mn);
        m[r] = mn;
      }
      float rs[4] = {0.f, 0.f, 0.f, 0.f};
      #pragma unroll
      for (int j = 0; j < 4; ++j)
        #pragma unroll
        for (int r = 0; r < 4; ++r) {
          float pe = __expf(s[j][r] - m[r]);
          s[j][r] = pe;
          rs[r] += pe;
        }
      #pragma unroll
      for (int off = 1; off <= 8; off <<= 1)
        #pragma unroll
        for (int r = 0; r < 4; ++r)
          rs[r] += __shfl_xor(rs[r], off);
      #pragma unroll
      for (int r = 0; r < 4; ++r) l[r] = l[r] * al[r] + rs[r];

      #pragma unroll
      for (int j = 0; j < 4; ++j)
        #pragma unroll
        for (int r = 0; r < 4; ++r)
          oacc[j][r] *= al[r];

      #pragma unroll
      for (int j = 0; j < 4; ++j)
        #pragma unroll
        for (int r = 0; r < 4; ++r)
          Ps[w][lg * 4 + r][j * 16 + lr] = f2bf(s[j][r]);

      #pragma unroll
      for (int c = 0; c < 2; ++c) {
        short8 a = *(const short8*)&Ps[w][lr][c * 32 + lg * 8];
        #pragma unroll
        for (int j = 0; j < 4; ++j) {
          short8 bb = *(const short8*)&Vs[j * 16 + lr][c * 32 + lg * 8];
          oacc[j] = __builtin_amdgcn_mfma_f32_16x16x32_bf16(a, bb, oacc[j], 0, 0, 0);
        }
      }
    }
  }

  float inv[4];
  #pragma unroll
  for (int r = 0; r < 4; ++r) inv[r] = 1.f / l[r];
  #pragma unroll
  for (int j = 0; j < 4; ++j)
    #pragma unroll
    for (int r = 0; r < 4; ++r) {
      size_t row = rowbase + qt_w * 64 + wr4 * 16 + lg * 4 + r;
      o[row * DMODEL + h * 64 + j * 16 + lr] = f2bf(oacc[j][r] * inv[r]);
    }
}

// ---------------------------------------------------------------------------
struct LNA {
  const u16* x;
  u16* xn;
  const float* ls[7];
  const float* lb[7];
};

__global__ __launch_bounds__(256) void ln_kernel(LNA p) {
  const int tid = threadIdx.x;
  const int rr = tid >> 6, lane = tid & 63;
  const size_t row = (size_t)blockIdx.x * 4 + rr;
  u32 wv = *(const u32*)&p.x[row * DMODEL + 2 * lane];
  float a = b2f((u16)wv), b = b2f((u16)(wv >> 16));
  float s = a + b;
  #pragma unroll
  for (int off = 32; off; off >>= 1) s += __shfl_xor(s, off);
  float mean = s * (1.f / 128.f);
  float da = a - mean, db = b - mean;
  float vs = da * da + db * db;
  #pragma unroll
  for (int off = 32; off; off >>= 1) vs += __shfl_xor(vs, off);
  float rstd = rsqrtf(vs * (1.f / 128.f) + 1e-5f);
  int band = (int)(row >> 13);
  const float* ls = p.ls[band];
  const float* lb = p.lb[band];
  *(u32*)&p.xn[row * DMODEL + 2 * lane] =
      pack2(da * rstd * ls[2 * lane] + lb[2 * lane],
            db * rstd * ls[2 * lane + 1] + lb[2 * lane + 1]);
}

// ---------------------------------------------------------------------------
extern "C" void kernel_launch(void* const* d_in, const int* in_sizes, int n_in,
                              void* d_out, int out_size, void* d_ws, size_t ws_size,
                              hipStream_t stream) {
  bool dict = (in_sizes[2] != 896);
  const float* bands = (const float*)d_in[0];
  const float* Wq = (const float*)d_in[1];
  const float *Wk, *Wv, *Wo, *bq, *bk, *bv, *bo;
  if (dict) {
    Wk = (const float*)d_in[2]; Wv = (const float*)d_in[3]; Wo = (const float*)d_in[4];
    bq = (const float*)d_in[5]; bk = (const float*)d_in[6];
    bv = (const float*)d_in[7]; bo = (const float*)d_in[8];
  } else {
    bq = (const float*)d_in[2]; Wk = (const float*)d_in[3]; bk = (const float*)d_in[4];
    Wv = (const float*)d_in[5]; bv = (const float*)d_in[6];
    Wo = (const float*)d_in[7]; bo = (const float*)d_in[8];
  }
  const float* g_ls = (const float*)d_in[9];
  const float* g_lb = (const float*)d_in[10];
  const float* g_w1 = (const float*)d_in[11];
  const float* g_b1 = (const float*)d_in[12];
  const float* g_w2 = (const float*)d_in[13];
  const float* g_b2 = (const float*)d_in[14];
  const float* g_wg = (const float*)d_in[15];
  const float* g_bg = (const float*)d_in[16];
  const float* h_ls = (const float*)d_in[17];
  const float* h_lb = (const float*)d_in[18];
  const float* h_w1 = (const float*)d_in[19];
  const float* h_b1 = (const float*)d_in[20];
  const float* h_w2 = (const float*)d_in[21];
  const float* h_b2 = (const float*)d_in[22];
  const float* r_ls = (const float*)d_in[23];
  const float* r_lb = (const float*)d_in[24];
  const float* r_w1 = (const float*)d_in[25];
  const float* r_b1 = (const float*)d_in[26];
  const float* r_w2 = (const float*)d_in[27];
  const float* r_b2 = (const float*)d_in[28];
  const float* wp_w = (const float*)d_in[29];
  const float* wp_b = (const float*)d_in[30];
  const float* wg_w = (const float*)d_in[31];
  const float* wg_b = (const float*)d_in[32];
  const float* br_w = (const float*)d_in[33];
  const float* br_b = (const float*)d_in[34];
  const float* bg_w = (const float*)d_in[35];
  const float* bg_b = (const float*)d_in[36];
  float* out = (float*)d_out;

  const float* lsP[7] = {g_ls, g_ls + 128, g_ls + 256, h_ls, h_ls + 128, r_ls, r_ls + 128};
  const float* lbP[7] = {g_lb, g_lb + 128, g_lb + 256, h_lb, h_lb + 128, r_lb, r_lb + 128};
  const float* b1p[7] = {g_b1, g_b1 + 256, g_b1 + 512,
                         h_b1, h_b1 + 384, r_b1, r_b1 + 512};
  const float* b2p[7] = {g_b2, g_b2 + 128, g_b2 + 256,
                         h_b2, h_b2 + 128, r_b2, r_b2 + 128};
  const int hN[7] = {256, 256, 256, 384, 384, 512, 512};

  // ---- workspace: bf16 activations (hidden arena holds ALL bands) ----
  const size_t HIDSZ = (size_t)MBAND * 2560;   // 3*256 + 2*384 + 2*512
  u16* H = (u16*)d_ws;
  u16* hidh = H;                         // HIDSZ (later overlays info/bridge)
  u16* qh = H + HIDSZ;
  u16* kh = qh + 7 * BANDE;
  u16* vh = kh + 7 * BANDE;              // holds vT[band][h][dim][m]
  u16* oh = vh + 7 * BANDE;
  u16* wt = oh + 7 * BANDE;              // transposed weights (bf16 [N][K])
  u16* wtQ   = wt;
  u16* wtK   = wtQ + 7 * 16384;
  u16* wtV   = wtK + 7 * 16384;
  u16* wtO   = wtV + 7 * 16384;
  u16* wtGwg = wtO + 7 * 16384;
  u16* wtWp  = wtGwg + 3 * 16384;
  u16* wtBr  = wtWp + 3 * 16384;
  u16* wtWg  = wtBr + 6 * 16384;         // 3 i x 2 K-parts
  u16* wtBg  = wtWg + 6 * 16384;         // 2 K-parts
  u16* wtG1  = wtBg + 2 * 16384;
  u16* wtH1  = wtG1 + 3 * 32768;
  u16* wtR1  = wtH1 + 2 * 49152;
  u16* wtG2  = wtR1 + 2 * 65536;
  u16* wtH2  = wtG2 + 3 * 32768;
  u16* wtR2  = wtH2 + 2 * 49152;
  u16* xh = qh;
  u16* xnh = kh;
  u16* gateh = vh;
  u16* yh = oh;
  u16* infoh = hidh;
  u16* bridgeh = hidh + 6 * BANDE;

  size_t hOff[7];
  {
    size_t acc = 0;
    for (int n = 0; n < 7; ++n) { hOff[n] = acc; acc += (size_t)MBAND * hN[n]; }
  }
  u16* wtW1s[7] = {wtG1, wtG1 + 32768, wtG1 + 65536,
                   wtH1, wtH1 + 49152, wtR1, wtR1 + 65536};
  u16* wtW2s[7] = {wtG2, wtG2 + 32768, wtG2 + 65536,
                   wtH2, wtH2 + 49152, wtR2, wtR2 + 49152 + 65536 - 49152};

  // fix: wtW2s for rea band 6 slice
  wtW2s[6] = wtR2 + 65536;

  auto LP = [&](PArgs& p, int Z, int ymax) {
    dim3 grid(MBAND / 64, ymax, Z);
    gemm_b<<<grid, dim3(256), 0, stream>>>(p);
  };

  // 0. transpose all weights once
  {
    TArgs ta{};
    int ns = 0;
    auto add = [&](const float* s, u16* d, int K, int N) {
      ta.s[ns].src = s; ta.s[ns].dst = d; ta.s[ns].K = K; ta.s[ns].N = N; ++ns;
    };
    for (int z = 0; z < 7; ++z) add(Wq + z * 16384, wtQ + z * 16384, 128, 128);
    for (int z = 0; z < 7; ++z) add(Wk + z * 16384, wtK + z * 16384, 128, 128);
    for (int z = 0; z < 7; ++z) add(Wv + z * 16384, wtV + z * 16384, 128, 128);
    for (int z = 0; z < 7; ++z) add(Wo + z * 16384, wtO + z * 16384, 128, 128);
    for (int i = 0; i < 3; ++i) add(g_wg + i * 16384, wtGwg + i * 16384, 128, 128);
    for (int i = 0; i < 3; ++i) add(wp_w + i * 16384, wtWp + i * 16384, 128, 128);
    for (int j = 0; j < 6; ++j) add(br_w + j * 16384, wtBr + j * 16384, 128, 128);
    for (int i = 0; i < 3; ++i) {
      add(wg_w + i * 32768,         wtWg + (size_t)(2 * i) * 16384,     128, 128);
      add(wg_w + i * 32768 + 16384, wtWg + (size_t)(2 * i + 1) * 16384, 128, 128);
    }
    add(bg_w,         wtBg,         128, 128);
    add(bg_w + 16384, wtBg + 16384, 128, 128);
    for (int i = 0; i < 3; ++i) add(g_w1 + i * 32768, wtG1 + i * 32768, 128, 256);
    for (int i = 0; i < 2; ++i) add(h_w1 + i * 49152, wtH1 + i * 49152, 128, 384);
    for (int i = 0; i < 2; ++i) add(r_w1 + i * 65536, wtR1 + i * 65536, 128, 512);
    for (int i = 0; i < 3; ++i) add(g_w2 + i * 32768, wtG2 + i * 32768, 256, 128);
    for (int i = 0; i < 2; ++i) add(h_w2 + i * 49152, wtH2 + i * 49152, 384, 128);
    for (int i = 0; i < 2; ++i) add(r_w2 + i * 65536, wtR2 + i * 65536, 512, 128);
    wtrans_kernel<<<dim3(64, 1, 62), dim3(256), 0, stream>>>(ta);
  }

  // 1. QKV merged: one dispatch, Z=21. A = fp32 bands (convert at staging).
  //    V entries store transposed (op 6, packed uint2).
  {
    PArgs p{};
    const u16* wtQKV[3] = {wtQ, wtK, wtV};
    const float* bqkv[3] = {bq, bk, bv};
    u16* oqkv[3] = {qh, kh, vh};
    for (int w = 0; w < 3; ++w)
      for (int band = 0; band < 7; ++band) {
        ZD& d = p.z[w * 7 + band];
        d.AF = bands + (size_t)band * BANDE;
        d.WT = wtQKV[w] + (size_t)band * 16384;
        d.bias = bqkv[w] + band * 128;
        d.OH = oqkv[w] + (size_t)band * BANDE;
        d.K = 128; d.N = 128; d.op = (w == 2) ? 6 : 0;
      }
    LP(p, 21, 2);
  }

  // 2. attention (paired q-tiles, 512 threads)
  attn_kernel<<<dim3(NBAND * BBATCH * 2 * 4), dim3(512), 0, stream>>>(qh, kh, vh, oh);

  // 3. x = bands + o @ Wo + bo
  {
    PArgs p{};
    for (int band = 0; band < 7; ++band) {
      ZD& d = p.z[band];
      d.A = oh + (size_t)band * BANDE;
      d.WT = wtO + (size_t)band * 16384;
      d.bias = bo + band * 128;
      d.residF = bands + (size_t)band * BANDE;
      d.OH = xh + (size_t)band * BANDE;
      d.K = 128; d.N = 128; d.op = 3;
    }
    LP(p, 7, 2);
  }

  // 4. LN
  {
    LNA p{};
    p.x = xh; p.xn = xnh;
    for (int n = 0; n < 7; ++n) { p.ls[n] = lsP[n]; p.lb[n] = lbP[n]; }
    ln_kernel<<<dim3(NBAND * MBAND / 4), dim3(256), 0, stream>>>(p);
  }

  // 5. geo gates + all MLP1 merged: Z=10, y=8 (early exit past N)
  {
    PArgs p{};
    for (int z = 0; z < 3; ++z) {
      ZD& d = p.z[z];
      d.A = xh + (size_t)z * BANDE;
      d.WT = wtGwg + (size_t)z * 16384;
      d.bias = g_bg + z * 128;
      d.OH = gateh + (size_t)z * BANDE;
      d.K = 128; d.N = 128; d.op = 2;
    }
    for (int band = 0; band < 7; ++band) {
      ZD& d = p.z[3 + band];
      d.A = xnh + (size_t)band * BANDE;
      d.WT = wtW1s[band];
      d.bias = b1p[band];
      d.OH = hidh + hOff[band];
      d.K = 128; d.N = hN[band]; d.op = 1;
    }
    LP(p, 10, 8);
  }

  // 6. MLP2 merged: Z=7 (per-z K)
  {
    PArgs p{};
    for (int band = 0; band < 7; ++band) {
      ZD& d = p.z[band];
      d.A = hidh + hOff[band];
      d.WT = wtW2s[band];
      d.bias = b2p[band];
      d.residH = xh + (size_t)band * BANDE;
      d.extraH = (band < 3) ? gateh + (size_t)band * BANDE : nullptr;
      d.OH = yh + (size_t)band * BANDE;
      d.K = hN[band]; d.N = 128; d.op = 5;
    }
    LP(p, 7, 2);
  }

  // 7. info (z=0..5) + bridge (z=6, op 7): one dispatch
  {
    PArgs p{};
    for (int z = 0; z < 6; ++z) {
      int t = (z < 3) ? z : z + 1;
      int src = 6 - t;
      int i = (t < 3) ? t : 6 - t;
      ZD& d = p.z[z];
      d.A = yh + (size_t)src * BANDE;
      d.WT = wtWp + (size_t)i * 16384;
      d.bias = wp_b + i * 128;
      d.OH = infoh + (size_t)z * BANDE;
      d.K = 128; d.N = 128; d.op = 0;
    }
    {
      ZD& d = p.z[6];
      d.A = yh;
      d.WT = wtBr;
      d.bias = br_b;
      d.OH = bridgeh;
      d.K = 128; d.N = 128; d.op = 7;
    }
    LP(p, 7, 2);
  }

  // 8. final gates + band-3 merged: Z=7, fp32 out
  {
    PArgs p{};
    for (int z = 0; z < 6; ++z) {
      int t = (z < 3) ? z : z + 1;
      int i = (t < 3) ? t : 6 - t;
      ZD& d = p.z[z];
      d.A = yh + (size_t)t * BANDE;
      d.WT = wtWg + (size_t)(2 * i) * 16384;
      d.A2 = infoh + (size_t)z * BANDE;
      d.WT2 = wtWg + (size_t)(2 * i + 1) * 16384;
      d.bias = wg_b + i * 128;
      d.residH = yh + (size_t)t * BANDE;
      d.extraH = infoh + (size_t)z * BANDE;
      d.OF = out + (size_t)t * BANDE;
      d.K = 128; d.N = 128; d.op = 4;
    }
    {
      ZD& d = p.z[6];
      d.A = yh + 3 * BANDE;
      d.WT = wtBg;
      d.A2 = bridgeh;
      d.WT2 = wtBg + 16384;
      d.bias = bg_b;
      d.residH = yh + 3 * BANDE;
      d.extraH = bridgeh;
      d.OF = out + 3 * BANDE;
      d.K = 128; d.N = 128; d.op = 4;
    }
    LP(p, 7, 2);
  }
}